// Round 8
// baseline (37217.825 us; speedup 1.0000x reference)
//
#include <hip/hip_runtime.h>

// Emulate numpy f32 per-op rounding exactly: no implicit mul+add fusion.
#pragma clang fp contract(off)

typedef unsigned short u16;
typedef unsigned int u32;
typedef unsigned long long u64;

#define BB 512
#define CC 128
#define TT 500
#define NN 512

#define TBL_BYTES 1050624ull          // 513*512*4
#define PAD_OFF (512u << 11)          // byte offset of the all-zero row

// dynamic LDS: W1hi (16 c4 x 512 n x float4 = 131072 B) + xs (2 par x 2 batch x 128 = 2048 B)
#define MEGA_DYN_BYTES (131072 + 2048)

// ---------------- prep kernel ----------------
// Transposed weights with a 513th all-zero row used as the padding target so
// sparse loops run in groups of 8 branch-free (adding 0.0f is exact).
__global__ void prep_weights(const float* __restrict__ W2, const float* __restrict__ Wr2,
                             float* __restrict__ Wr2T, float* __restrict__ W2T) {
  int i = blockIdx.x * blockDim.x + threadIdx.x;
  if (i < 513 * 512) {
    int k = i >> 9, n = i & 511;
    Wr2T[i] = (k < NN) ? Wr2[n * NN + k] : 0.0f;
    W2T[i]  = (k < NN) ? W2[n * NN + k] : 0.0f;
  }
}

// ---------------- sparse row-sum (r0-proven, bit-exact order) ----
// The gather is aggregate-L2-BW-bound (r6: 70GB/2.0ms = 34.8 TB/s ~= ceiling;
// r3 vs r4: different schedules, identical time).  Minimal-traffic form.
template <int PRE>
__device__ __forceinline__ float sparse_sum_pre(const float* __restrict__ mat,
                                                const u32* list, int cnt, u32 n4) {
  if (cnt <= 0) return 0.0f;
  const char* base = (const char*)mat;
  const int ng = (cnt + 7) >> 3;
  const int npre = ng < PRE ? ng : PRE;
  float buf[PRE * 8];
#pragma unroll
  for (int g = 0; g < PRE; ++g) {
    if (g < npre) {
      uint4 qa = *(const uint4*)(list + g * 8);
      uint4 qb = *(const uint4*)(list + g * 8 + 4);
      buf[g * 8 + 0] = *(const float*)(base + (qa.x + n4));
      buf[g * 8 + 1] = *(const float*)(base + (qa.y + n4));
      buf[g * 8 + 2] = *(const float*)(base + (qa.z + n4));
      buf[g * 8 + 3] = *(const float*)(base + (qa.w + n4));
      buf[g * 8 + 4] = *(const float*)(base + (qb.x + n4));
      buf[g * 8 + 5] = *(const float*)(base + (qb.y + n4));
      buf[g * 8 + 6] = *(const float*)(base + (qb.z + n4));
      buf[g * 8 + 7] = *(const float*)(base + (qb.w + n4));
    }
  }
  float s = 0.0f;
#pragma unroll
  for (int g = 0; g < PRE; ++g) {
    if (g < npre) {
#pragma unroll
      for (int j = 0; j < 8; ++j) s += buf[g * 8 + j];
    }
  }
  for (int i = PRE * 8; i < cnt; i += 8) {  // rare tail
    uint4 qa = *(const uint4*)(list + i);
    uint4 qb = *(const uint4*)(list + i + 4);
    float f0 = *(const float*)(base + (qa.x + n4));
    float f1 = *(const float*)(base + (qa.y + n4));
    float f2 = *(const float*)(base + (qa.z + n4));
    float f3 = *(const float*)(base + (qa.w + n4));
    float f4 = *(const float*)(base + (qb.x + n4));
    float f5 = *(const float*)(base + (qb.y + n4));
    float f6 = *(const float*)(base + (qb.z + n4));
    float f7 = *(const float*)(base + (qb.w + n4));
    s += f0; s += f1; s += f2; s += f3;
    s += f4; s += f5; s += f6; s += f7;
  }
  return s;
}

// position via v_mbcnt (2 VALU); word totals via readfirstlane -> s_bcnt1 (SALU).
__device__ __forceinline__ void build_list(const u64* words, int mybit, int wave,
                                           u32 nOff, int n, u32* slot, int* cnt) {
  int tot = 0, base = 0;
#pragma unroll
  for (int j = 0; j < 8; ++j) {
    u64 w = words[j];
    u32 lo = __builtin_amdgcn_readfirstlane((u32)w);
    u32 hi = __builtin_amdgcn_readfirstlane((u32)(w >> 32));
    int pj = __popc(lo) + __popc(hi);
    if (j < wave) base += pj;
    tot += pj;
  }
  if (tot) {
    if (mybit) {
      u64 w = words[wave];
      int below = __builtin_amdgcn_mbcnt_hi((u32)(w >> 32),
                    __builtin_amdgcn_mbcnt_lo((u32)w, 0u));
      slot[base + below] = nOff;
    }
    if (n < 8) slot[tot + n] = PAD_OFF;  // pad -> zero row
  }
  if (n == 0) *cnt = tot;
}

// ---------------- fused mega kernel: GEMV + recurrence, 2 batches/block ----
// Eliminates the separate ~680us gemm and the 1GB i1ff HBM round-trip by
// computing ff = x_t @ W1[n]^T in-step as ONE ascending-c fmaf chain:
//   c 0..63  from 64 VGPRs/thread (w1q[16] float4),
//   c 64..127 from a 128KB LDS copy of W1[:,64:128] (shared by both batches).
// Grid 256 = 1 block/CU of 1024 threads (16 waves/CU — same wave count and
// outstanding-load pressure as the old 2x512 config, so the L2-BW-bound
// gather runs at the same rate).  VGPR ~ 64 (w1) + 40 (r6 recur2) ~= 110
// under the 128 cap of (1024,4) -> no spill (r5's failure mode).
__global__ void __launch_bounds__(1024, 4)
recur_mega(const float* __restrict__ x, const float* __restrict__ W1,
           const float* __restrict__ Wr2T, const float* __restrict__ W2T,
           const float* __restrict__ W4,
           const float* __restrict__ b1, const float* __restrict__ b2,
           const float* __restrict__ br2, const float* __restrict__ b4,
           const float* __restrict__ Vth1, const float* __restrict__ tau1,
           const float* __restrict__ Vth2, const float* __restrict__ tau2,
           const float* __restrict__ tau_out, float* __restrict__ out) {
  const int tid = threadIdx.x;
  const int batch = tid >> 9;            // 0 or 1
  const int n = tid & 511;               // local neuron id
  const int lane = tid & 63;
  const int wl = (tid >> 6) & 7;         // wave index within batch group
  const int b = blockIdx.x + (batch << 8);   // b0 = blk, b1 = blk + 256
  const u32 n4 = (u32)(n << 2);
  const u32 nOff = (u32)(n << 11);

  extern __shared__ float dyn[];
  float4* W1h = (float4*)dyn;            // [16 c4][512 n], conflict-free b128
  float* xs = dyn + 32768;               // [2 parity][2 batch][128 c]

  __shared__ u64 wordsA[2][8], wordsB[2][8];
  __shared__ __align__(16) u32 listA[2][2][520];
  __shared__ __align__(16) u32 listB[2][2][520];
  __shared__ int cA[2][2], cB[2][2];

  // ---- stage W1[:,64:128] into LDS once (both batches share it) ----
  for (int k = 0; k < 8; ++k) {
    int idx = k * 1024 + tid;            // 0..8191
    int c4 = idx >> 9, nn = idx & 511;
    W1h[c4 * 512 + nn] = *(const float4*)(W1 + nn * CC + 64 + c4 * 4);
  }
  // ---- W1[n,0:64] into registers ----
  float4 w1q[16];
  {
    const float4* wp = (const float4*)(W1 + n * CC);
#pragma unroll
    for (int i = 0; i < 16; ++i) w1q[i] = wp[i];
  }

  // ---- init state ----
  if (tid < 32) {
    int g = tid >> 3, w = tid & 7;
    if (g == 0) wordsA[0][w] = 0ull;
    else if (g == 1) wordsA[1][w] = 0ull;
    else if (g == 2) wordsB[0][w] = 0ull;
    else wordsB[1][w] = 0ull;
  }
  if (n == 0) { cA[batch][0] = 0; cB[batch][0] = 0; }
  if (n < CC) xs[(0 * 2 + batch) * CC + n] = x[(b * CC + n) * TT + 0];  // prime t=0

  float mem1 = 0.0f, mem2 = 0.0f;
  int sp1 = 0, sp2 = 0, sc1 = 0, sc2 = 0;
  const int ro = n >> 6;
  const bool isRd = (n == 0) || (n == 64);
  float memo = 0.0f;

  const float b1v = b1[n], b2v = b2[n], br2v = br2[n];
  const float t1 = tau1[n], t2 = tau2[n];
  const float v1 = Vth1[n], v2 = Vth2[n];
  const float tov = tau_out[ro & 1];
  const float b4v = b4[ro & 1];

  for (int t = 0; t < TT; ++t) {
    const int pp = t & 1, qq = pp ^ 1;
    const int tn = (t + 1 < TT) ? t + 1 : t;
    float xnext = 0.0f;
    if (n < CC) xnext = x[(b * CC + n) * TT + tn];  // in flight across the step
    __syncthreads();  // B0: xs[pp], lists[pp], W1h (t=0) ready

    // ---- layer 1: ff = x_t @ W1[n]^T  (ONE ascending-c fmaf chain) ----
    const float4* xb4 = (const float4*)(xs + (pp * 2 + batch) * CC);
    float ff1 = 0.0f;
#pragma unroll
    for (int c4 = 0; c4 < 16; ++c4) {    // c = 0..63 from registers
      float4 xq = xb4[c4];
      float4 wq = w1q[c4];
      ff1 = __builtin_fmaf(xq.x, wq.x, ff1);
      ff1 = __builtin_fmaf(xq.y, wq.y, ff1);
      ff1 = __builtin_fmaf(xq.z, wq.z, ff1);
      ff1 = __builtin_fmaf(xq.w, wq.w, ff1);
    }
#pragma unroll
    for (int c4 = 0; c4 < 16; ++c4) {    // c = 64..127 from LDS
      float4 xq = xb4[16 + c4];
      float4 wq = W1h[c4 * 512 + n];
      ff1 = __builtin_fmaf(xq.x, wq.x, ff1);
      ff1 = __builtin_fmaf(xq.y, wq.y, ff1);
      ff1 = __builtin_fmaf(xq.z, wq.z, ff1);
      ff1 = __builtin_fmaf(xq.w, wq.w, ff1);
    }

    float r1 = sparse_sum_pre<6>(Wr2T, listA[batch][pp], cA[batch][pp], n4);
    float u1 = ff1 + b1v;
    float w1s = r1 + br2v;
    float i1 = u1 + w1s;
    float a1m = t1 * mem1;
    a1m = sp1 ? 0.0f : a1m;
    float m1 = a1m + i1;
    mem1 = m1;
    const int s1 = (m1 - v1) > 0.0f ? 1 : 0;
    u64 ba = __ballot(s1 != 0);
    if (lane == 0) wordsA[batch][wl] = ba;
    __syncthreads();  // B1

    build_list(&wordsA[batch][0], s1, wl, nOff, n, listA[batch][qq], &cA[batch][qq]);
    __syncthreads();  // B1b

    // ---- layer 2: i2 = (s1@W2^T + b2) + (sp2@Wr2^T + br2) ----
    float ff = sparse_sum_pre<6>(W2T, listA[batch][qq], cA[batch][qq], n4);
    float u2 = ff + b2v;
    float r2 = sparse_sum_pre<6>(Wr2T, listB[batch][pp], cB[batch][pp], n4);
    float w2s = r2 + br2v;
    float i2 = u2 + w2s;
    float a2m = t2 * mem2;
    a2m = sp2 ? 0.0f : a2m;
    float m2 = a2m + i2;
    mem2 = m2;
    const int s2 = (m2 - v2) > 0.0f ? 1 : 0;
    u64 bb = __ballot(s2 != 0);
    if (lane == 0) wordsB[batch][wl] = bb;
    sp1 = s1; sp2 = s2; sc1 += s1; sc2 += s2;
    __syncthreads();  // B2

    build_list(&wordsB[batch][0], s2, wl, nOff, n, listB[batch][qq], &cB[batch][qq]);
    if (n < CC) xs[(qq * 2 + batch) * CC + n] = xnext;  // ordered by next B0

    // ---- readout: memo = (tau_out*memo) + ((s2@W4^T) + b4) ----
    if (isRd) {
      const float* w4r = W4 + ro * NN;
      float a = 0.0f;  // ascending-k f32 chain (s2 sparse)
#pragma unroll
      for (int w = 0; w < 8; ++w) {
        u64 m = wordsB[batch][w];
        while (m) {
          int k = (w << 6) + __builtin_ctzll(m);
          m &= m - 1ull;
          a += w4r[k];
        }
      }
      float z = tov * memo;
      memo = z + (a + b4v);
      out[(b * 2 + ro) * TT + t] = memo;
    }
  }

  out[BB * 2 * TT + b * NN + n]           = (float)sc1 / 500.0f;
  out[BB * 2 * TT + BB * NN + b * NN + n] = (float)sc2 / 500.0f;
}

// ---------------- fallback monolithic kernel (tiny ws): no-spill GEMV ----------------
__global__ void __launch_bounds__(512) __attribute__((amdgpu_waves_per_eu(2, 2)))
recur_fb(const float* __restrict__ x, const float* __restrict__ W1,
         const float* __restrict__ Wr2T, const float* __restrict__ W2T,
         const float* __restrict__ W4,
         const float* __restrict__ b1, const float* __restrict__ b2,
         const float* __restrict__ br2, const float* __restrict__ b4,
         const float* __restrict__ Vth1, const float* __restrict__ tau1,
         const float* __restrict__ Vth2, const float* __restrict__ tau2,
         const float* __restrict__ tau_out, float* __restrict__ out) {
  const int n = threadIdx.x, b = blockIdx.x;
  const int lane = n & 63, wave = n >> 6;
  const u32 n4 = (u32)(n << 2);
  const u32 nOff = (u32)(n << 11);

  __shared__ float xs[CC];
  __shared__ u64 wordsA[8], wordsB[8];
  __shared__ __align__(16) u32 listA[2][520];
  __shared__ __align__(16) u32 listB[2][520];
  __shared__ int cA[2], cB[2];

  float w1r[CC];  // fits: waves_per_eu(2,2) -> 256-VGPR budget, no spill
  {
    const float4* wp = (const float4*)(W1 + n * CC);
#pragma unroll
    for (int i = 0; i < CC / 4; ++i) {
      float4 q = wp[i];
      w1r[i * 4 + 0] = q.x; w1r[i * 4 + 1] = q.y;
      w1r[i * 4 + 2] = q.z; w1r[i * 4 + 3] = q.w;
    }
  }

  float mem1 = 0.0f, mem2 = 0.0f;
  const float b1v = b1[n], b2v = b2[n], br2v = br2[n];
  const float t1 = tau1[n], t2 = tau2[n];
  const float v1 = Vth1[n], v2 = Vth2[n];
  const float to0 = tau_out[0], to1 = tau_out[1];
  const float b40 = b4[0], b41 = b4[1];
  int sp1 = 0, sp2 = 0, sc1 = 0, sc2 = 0;
  float memo0 = 0.0f, memo1 = 0.0f;

  if (n == 0) { cA[0] = 0; cB[0] = 0; }
  if (n < 8) wordsA[n] = 0ull;
  else if (n < 16) wordsB[n - 8] = 0ull;

  for (int t = 0; t < TT; ++t) {
    const int pp = t & 1, qq = pp ^ 1;
    if (n < CC) xs[n] = x[(b * CC + n) * TT + t];
    __syncthreads();

    float acc = 0.0f;
#pragma unroll
    for (int c = 0; c < CC; ++c) acc = __builtin_fmaf(xs[c], w1r[c], acc);
    float u1 = acc + b1v;
    float r1 = sparse_sum_pre<6>(Wr2T, listA[pp], cA[pp], n4);
    float w1s = r1 + br2v;
    float i1 = u1 + w1s;
    float a1m = t1 * mem1;
    a1m = sp1 ? 0.0f : a1m;
    float m1 = a1m + i1;
    mem1 = m1;
    const int s1 = (m1 - v1) > 0.0f ? 1 : 0;
    u64 ba = __ballot(s1 != 0);
    if (lane == 0) wordsA[wave] = ba;
    __syncthreads();

    build_list(wordsA, s1, wave, nOff, n, listA[qq], &cA[qq]);
    __syncthreads();

    float ff = sparse_sum_pre<6>(W2T, listA[qq], cA[qq], n4);
    float u2 = ff + b2v;
    float r2 = sparse_sum_pre<6>(Wr2T, listB[pp], cB[pp], n4);
    float w2s = r2 + br2v;
    float i2 = u2 + w2s;
    float a2m = t2 * mem2;
    a2m = sp2 ? 0.0f : a2m;
    float m2 = a2m + i2;
    mem2 = m2;
    const int s2 = (m2 - v2) > 0.0f ? 1 : 0;
    u64 bb = __ballot(s2 != 0);
    if (lane == 0) wordsB[wave] = bb;
    sp1 = s1; sp2 = s2; sc1 += s1; sc2 += s2;
    __syncthreads();

    build_list(wordsB, s2, wave, nOff, n, listB[qq], &cB[qq]);

    if (n == 0) {
      float a0 = 0.0f, a1 = 0.0f;
#pragma unroll
      for (int w = 0; w < 8; ++w) {
        u64 m = wordsB[w];
        while (m) {
          int k = (w << 6) + __builtin_ctzll(m);
          m &= m - 1ull;
          a0 += W4[k];
          a1 += W4[NN + k];
        }
      }
      float z0 = to0 * memo0;
      float z1 = to1 * memo1;
      memo0 = z0 + (a0 + b40);
      memo1 = z1 + (a1 + b41);
      out[(b * 2 + 0) * TT + t] = memo0;
      out[(b * 2 + 1) * TT + t] = memo1;
    }
  }

  out[BB * 2 * TT + b * NN + n]           = (float)sc1 / 500.0f;
  out[BB * 2 * TT + BB * NN + b * NN + n] = (float)sc2 / 500.0f;
}

// ---------------- launcher ----------------
extern "C" void kernel_launch(void* const* d_in, const int* in_sizes, int n_in,
                              void* d_out, int out_size, void* d_ws, size_t ws_size,
                              hipStream_t stream) {
  (void)in_sizes; (void)n_in; (void)out_size;
  const float* x    = (const float*)d_in[0];
  const float* W1   = (const float*)d_in[1];
  const float* b1   = (const float*)d_in[2];
  const float* W2   = (const float*)d_in[3];
  const float* b2   = (const float*)d_in[4];
  const float* Wr2  = (const float*)d_in[5];
  const float* br2  = (const float*)d_in[6];
  // d_in[7..10] = W3,b3,Wr3,br3: dead code w.r.t. outputs — skipped
  const float* W4   = (const float*)d_in[11];
  const float* b4   = (const float*)d_in[12];
  const float* Vth1 = (const float*)d_in[13];
  const float* tau1 = (const float*)d_in[14];
  const float* Vth2 = (const float*)d_in[15];
  const float* tau2 = (const float*)d_in[16];
  const float* tau_out = (const float*)d_in[19];

  char* ws = (char*)d_ws;

  if (ws_size >= 2 * TBL_BYTES) {
    float* Wr2T = (float*)ws;
    float* W2T  = (float*)(ws + TBL_BYTES);
    hipLaunchKernelGGL(prep_weights, dim3((513 * 512 + 255) / 256), dim3(256), 0, stream,
                       W2, Wr2, Wr2T, W2T);
    hipLaunchKernelGGL(recur_mega, dim3(256), dim3(1024), MEGA_DYN_BYTES, stream,
                       x, W1, Wr2T, W2T, W4, b1, b2, br2, b4,
                       Vth1, tau1, Vth2, tau2, tau_out, (float*)d_out);
  } else {
    // ws too small even for the weight tables: cannot run (tables are required).
    // Degenerate path: still try fallback with tables at ws start (requires 2.1MB).
    float* Wr2T = (float*)ws;
    float* W2T  = (float*)(ws + TBL_BYTES);
    hipLaunchKernelGGL(prep_weights, dim3((513 * 512 + 255) / 256), dim3(256), 0, stream,
                       W2, Wr2, Wr2T, W2T);
    hipLaunchKernelGGL(recur_fb, dim3(BB), dim3(512), 0, stream,
                       x, W1, Wr2T, W2T, W4, b1, b2, br2, b4,
                       Vth1, tau1, Vth2, tau2, tau_out, (float*)d_out);
  }
}

// Round 9
// 2712.135 us; speedup vs baseline: 13.7227x; 13.7227x over previous
//
#include <hip/hip_runtime.h>

// Emulate numpy f32 per-op rounding exactly: no implicit mul+add fusion.
#pragma clang fp contract(off)

typedef unsigned short u16;
typedef unsigned int u32;
typedef unsigned long long u64;

#define BB 512
#define CC 128
#define TT 500
#define NN 512
#define T_TILE 32

#define TBL_BYTES 1050624ull          // 513*512*4
#define CHUNK_ROW_BYTES 1048576ull    // 512*512*4 per timestep
#define ST_ARR_BYTES 1048576ull       // 512*512*4 per state array
#define PAD_OFF (512u << 11)          // byte offset of the all-zero row

// ---------------- prep kernel ----------------
// Transposed weights with a 513th all-zero row used as the padding target so
// sparse loops run in groups of 8 branch-free (adding 0.0f is exact).
__global__ void prep_weights(const float* __restrict__ W2, const float* __restrict__ Wr2,
                             float* __restrict__ Wr2T, float* __restrict__ W2T) {
  int i = blockIdx.x * blockDim.x + threadIdx.x;
  if (i < 513 * 512) {
    int k = i >> 9, n = i & 511;
    Wr2T[i] = (k < NN) ? Wr2[n * NN + k] : 0.0f;
    W2T[i]  = (k < NN) ? W2[n * NN + k] : 0.0f;
  }
}

// ---------------- i1ff GEMM (chunked): i1ff[b][tl][n] = chain_c x[b][c][t]*W1[n][c] ----
// Bit-exact: each output is ONE ascending-c fmaf chain starting at 0.
// r6-proven best form: 256 threads, 2 n/thread (acc = 64 VGPRs, no spill
// under the (256,4) cap), 16 waves/CU, LDS 34KB -> 4 blocks/CU.
// r7 (one-shot 148KB LDS, 1 blk/CU) regressed; r5/r8 (reg fusion) spilled.
__global__ void __launch_bounds__(256, 4)
gemm_i1ff(const float* __restrict__ x, const float* __restrict__ W1,
          float* __restrict__ i1ff, int tBeg, int tLen) {
  const int b = blockIdx.x;
  const int tl0 = blockIdx.y * T_TILE;   // chunk-local t of tile start
  const int tid = threadIdx.x;           // 256 threads

  __shared__ __align__(16) float xs[CC * T_TILE];  // [c][j], 16 KB
  __shared__ float W1L[NN * 9];          // [n][cc], pitch 9 (odd -> conflict-free), 18 KB

  // stage x tile: consecutive threads -> consecutive t (coalesced)
  for (int i = tid; i < CC * T_TILE; i += 256) {
    int c = i >> 5, j = i & 31;
    int tl = tl0 + j;
    xs[c * T_TILE + j] = (tl < tLen) ? x[(b * CC + c) * TT + (tBeg + tl)] : 0.0f;
  }

  float acc[2][T_TILE];
#pragma unroll
  for (int r = 0; r < 2; ++r)
#pragma unroll
    for (int j = 0; j < T_TILE; ++j) acc[r][j] = 0.0f;

  for (int cp = 0; cp < CC / 8; ++cp) {
    __syncthreads();  // guards xs stores (cp==0) and previous-panel reads
    for (int i = tid; i < NN * 8; i += 256) {
      int nn = i >> 3, cc = i & 7;
      W1L[nn * 9 + cc] = W1[nn * CC + cp * 8 + cc];
    }
    __syncthreads();
#pragma unroll
    for (int cc = 0; cc < 8; ++cc) {
      const int c = cp * 8 + cc;
      float w0 = W1L[(tid + 0)   * 9 + cc];
      float w1 = W1L[(tid + 256) * 9 + cc];
      const float4* xp = (const float4*)(xs + c * T_TILE);
#pragma unroll
      for (int j4 = 0; j4 < T_TILE / 4; ++j4) {
        float4 xq = xp[j4];              // 16B broadcast, conflict-free
        const int j = j4 * 4;
        acc[0][j + 0] = __builtin_fmaf(xq.x, w0, acc[0][j + 0]);
        acc[1][j + 0] = __builtin_fmaf(xq.x, w1, acc[1][j + 0]);
        acc[0][j + 1] = __builtin_fmaf(xq.y, w0, acc[0][j + 1]);
        acc[1][j + 1] = __builtin_fmaf(xq.y, w1, acc[1][j + 1]);
        acc[0][j + 2] = __builtin_fmaf(xq.z, w0, acc[0][j + 2]);
        acc[1][j + 2] = __builtin_fmaf(xq.z, w1, acc[1][j + 2]);
        acc[0][j + 3] = __builtin_fmaf(xq.w, w0, acc[0][j + 3]);
        acc[1][j + 3] = __builtin_fmaf(xq.w, w1, acc[1][j + 3]);
      }
    }
  }

#pragma unroll
  for (int j = 0; j < T_TILE; ++j) {
    int tl = tl0 + j;
    if (tl < tLen) {
      float* o = i1ff + ((size_t)b * tLen + tl) * NN;
      o[tid + 0]   = acc[0][j];
      o[tid + 256] = acc[1][j];
    }
  }
}

// ---------------- sparse row-sum (pre-scaled u32 byte offsets, bit-exact order) ----
// recur2 is AT the aggregate-L2 roofline (r6: 70 GB/dispatch / 2.02 ms =
// 34.8 TB/s ~= the 34.5 TB/s ceiling; r3 vs r4: different schedules, same
// time).  Pads hit the L1-resident zero row (~free).  Do not touch.
template <int PRE>
__device__ __forceinline__ float sparse_sum_pre(const float* __restrict__ mat,
                                                const u32* list, int cnt, u32 n4) {
  if (cnt <= 0) return 0.0f;
  const char* base = (const char*)mat;
  const int ng = (cnt + 7) >> 3;
  const int npre = ng < PRE ? ng : PRE;
  float buf[PRE * 8];
#pragma unroll
  for (int g = 0; g < PRE; ++g) {
    if (g < npre) {
      uint4 qa = *(const uint4*)(list + g * 8);
      uint4 qb = *(const uint4*)(list + g * 8 + 4);
      buf[g * 8 + 0] = *(const float*)(base + (qa.x + n4));
      buf[g * 8 + 1] = *(const float*)(base + (qa.y + n4));
      buf[g * 8 + 2] = *(const float*)(base + (qa.z + n4));
      buf[g * 8 + 3] = *(const float*)(base + (qa.w + n4));
      buf[g * 8 + 4] = *(const float*)(base + (qb.x + n4));
      buf[g * 8 + 5] = *(const float*)(base + (qb.y + n4));
      buf[g * 8 + 6] = *(const float*)(base + (qb.z + n4));
      buf[g * 8 + 7] = *(const float*)(base + (qb.w + n4));
    }
  }
  float s = 0.0f;
#pragma unroll
  for (int g = 0; g < PRE; ++g) {
    if (g < npre) {
#pragma unroll
      for (int j = 0; j < 8; ++j) s += buf[g * 8 + j];
    }
  }
  for (int i = PRE * 8; i < cnt; i += 8) {  // rare tail
    uint4 qa = *(const uint4*)(list + i);
    uint4 qb = *(const uint4*)(list + i + 4);
    float f0 = *(const float*)(base + (qa.x + n4));
    float f1 = *(const float*)(base + (qa.y + n4));
    float f2 = *(const float*)(base + (qa.z + n4));
    float f3 = *(const float*)(base + (qa.w + n4));
    float f4 = *(const float*)(base + (qb.x + n4));
    float f5 = *(const float*)(base + (qb.y + n4));
    float f6 = *(const float*)(base + (qb.z + n4));
    float f7 = *(const float*)(base + (qb.w + n4));
    s += f0; s += f1; s += f2; s += f3;
    s += f4; s += f5; s += f6; s += f7;
  }
  return s;
}

// position via v_mbcnt (2 VALU); word totals via readfirstlane -> s_bcnt1 (SALU).
__device__ __forceinline__ void build_list(const u64* words, int mybit, int wave,
                                           u32 nOff, int n, u32* slot, int* cnt) {
  int tot = 0, base = 0;
#pragma unroll
  for (int j = 0; j < 8; ++j) {
    u64 w = words[j];
    u32 lo = __builtin_amdgcn_readfirstlane((u32)w);
    u32 hi = __builtin_amdgcn_readfirstlane((u32)(w >> 32));
    int pj = __popc(lo) + __popc(hi);
    if (j < wave) base += pj;
    tot += pj;
  }
  if (tot) {
    if (mybit) {
      u64 w = words[wave];
      int below = __builtin_amdgcn_mbcnt_hi((u32)(w >> 32),
                    __builtin_amdgcn_mbcnt_lo((u32)w, 0u));
      slot[base + below] = nOff;
    }
    if (n < 8) slot[tot + n] = PAD_OFF;  // pad -> zero row
  }
  if (n == 0) *cnt = tot;
}

// ---------------- chunked recurrent kernel (r6-proven, untouched) ----------------
__global__ void __launch_bounds__(512, 2)
recur2(const float* __restrict__ i1ff, const float* __restrict__ Wr2T,
       const float* __restrict__ W2T, const float* __restrict__ W4,
       const float* __restrict__ b1, const float* __restrict__ b2,
       const float* __restrict__ br2, const float* __restrict__ b4,
       const float* __restrict__ Vth1, const float* __restrict__ tau1,
       const float* __restrict__ Vth2, const float* __restrict__ tau2,
       const float* __restrict__ tau_out, float* __restrict__ out,
       float* __restrict__ stM1, float* __restrict__ stM2,
       u32* __restrict__ stSC1, u32* __restrict__ stSC2,
       u64* __restrict__ stW, float* __restrict__ stMemo,
       int tBeg, int tLen, int isFirst, int isLast) {
  const int n = threadIdx.x, b = blockIdx.x;
  const int lane = n & 63, wave = n >> 6;
  const u32 n4 = (u32)(n << 2);
  const u32 nOff = (u32)(n << 11);

  __shared__ u64 wordsA[8], wordsB[8];
  __shared__ __align__(16) u32 listA[2][520];
  __shared__ __align__(16) u32 listB[2][520];
  __shared__ int cA[2], cB[2];

  float mem1, mem2;
  int sc1, sc2;
  float memo0 = 0.0f, memo1 = 0.0f;
  if (isFirst) {
    mem1 = 0.0f; mem2 = 0.0f; sc1 = 0; sc2 = 0;
    if (n < 8) wordsA[n] = 0ull;
    else if (n < 16) wordsB[n - 8] = 0ull;
  } else {
    mem1 = stM1[b * NN + n]; mem2 = stM2[b * NN + n];
    sc1 = (int)stSC1[b * NN + n]; sc2 = (int)stSC2[b * NN + n];
    if (n < 8) wordsA[n] = stW[b * 16 + n];
    else if (n < 16) wordsB[n - 8] = stW[b * 16 + n];
    if (n == 0) { memo0 = stMemo[b * 2]; memo1 = stMemo[b * 2 + 1]; }
  }
  __syncthreads();
  int sp1 = (int)((wordsA[wave] >> lane) & 1ull);
  int sp2 = (int)((wordsB[wave] >> lane) & 1ull);
  // initial lists into parity slot 0 (tBeg is always even)
  build_list(wordsA, sp1, wave, nOff, n, listA[0], &cA[0]);
  build_list(wordsB, sp2, wave, nOff, n, listB[0], &cB[0]);
  // first in-loop B0 orders these before use

  const float b1v = b1[n], b2v = b2[n], br2v = br2[n];
  const float t1 = tau1[n], t2 = tau2[n];
  const float v1 = Vth1[n], v2 = Vth2[n];
  const float to0 = tau_out[0], to1 = tau_out[1];
  const float b40 = b4[0], b41 = b4[1];

  const float* ffp = i1ff + (size_t)b * tLen * NN + n;
  float ffcur = ffp[0];

  for (int t = tBeg; t < tBeg + tLen; ++t) {
    const int tt = t - tBeg;
    const int pp = t & 1, qq = pp ^ 1;
    const int ttn = (tt + 1 < tLen) ? tt + 1 : tt;
    float ffnext = ffp[(size_t)ttn * NN];   // issued pre-barrier, used next iter
    __syncthreads();  // B0

    // ---- layer 1: i1 = (x@W1^T + b1) + (sp1@Wr2^T + br2) ----
    float r1 = sparse_sum_pre<6>(Wr2T, listA[pp], cA[pp], n4);
    float u1 = ffcur + b1v;
    float w1s = r1 + br2v;
    float i1 = u1 + w1s;
    float a1m = t1 * mem1;
    a1m = sp1 ? 0.0f : a1m;
    float m1 = a1m + i1;
    mem1 = m1;
    const int s1 = (m1 - v1) > 0.0f ? 1 : 0;
    u64 ba = __ballot(s1 != 0);
    if (lane == 0) wordsA[wave] = ba;
    __syncthreads();  // B1

    build_list(wordsA, s1, wave, nOff, n, listA[qq], &cA[qq]);
    __syncthreads();  // B1b

    // ---- layer 2: i2 = (s1@W2^T + b2) + (sp2@Wr2^T + br2) ----
    float ff = sparse_sum_pre<6>(W2T, listA[qq], cA[qq], n4);
    float u2 = ff + b2v;
    float r2 = sparse_sum_pre<6>(Wr2T, listB[pp], cB[pp], n4);
    float w2s = r2 + br2v;
    float i2 = u2 + w2s;
    float a2m = t2 * mem2;
    a2m = sp2 ? 0.0f : a2m;
    float m2 = a2m + i2;
    mem2 = m2;
    const int s2 = (m2 - v2) > 0.0f ? 1 : 0;
    u64 bb = __ballot(s2 != 0);
    if (lane == 0) wordsB[wave] = bb;
    sp1 = s1; sp2 = s2; sc1 += s1; sc2 += s2;
    ffcur = ffnext;
    __syncthreads();  // B2

    build_list(wordsB, s2, wave, nOff, n, listB[qq], &cB[qq]);

    // ---- readout: memo = (tau_out*memo) + ((s2@W4^T) + b4) ----
    if (n == 0) {
      float a0 = 0.0f, a1 = 0.0f;  // ascending-k f32 chains (s2 ~never fires)
#pragma unroll
      for (int w = 0; w < 8; ++w) {
        u64 m = wordsB[w];
        while (m) {
          int k = (w << 6) + __builtin_ctzll(m);
          m &= m - 1ull;
          a0 += W4[k];
          a1 += W4[NN + k];
        }
      }
      float z0 = to0 * memo0;
      float z1 = to1 * memo1;
      memo0 = z0 + (a0 + b40);
      memo1 = z1 + (a1 + b41);
      out[(b * 2 + 0) * TT + t] = memo0;
      out[(b * 2 + 1) * TT + t] = memo1;
    }
  }

  if (isLast) {
    out[BB * 2 * TT + b * NN + n]           = (float)sc1 / 500.0f;
    out[BB * 2 * TT + BB * NN + b * NN + n] = (float)sc2 / 500.0f;
  } else {
    __syncthreads();
    stM1[b * NN + n] = mem1; stM2[b * NN + n] = mem2;
    stSC1[b * NN + n] = (u32)sc1; stSC2[b * NN + n] = (u32)sc2;
    if (n < 8) stW[b * 16 + n] = wordsA[n];
    else if (n < 16) stW[b * 16 + n] = wordsB[n - 8];
    if (n == 0) { stMemo[b * 2] = memo0; stMemo[b * 2 + 1] = memo1; }
  }
}

// ---------------- fallback monolithic kernel (tiny ws): no-spill GEMV ----------------
__global__ void __launch_bounds__(512) __attribute__((amdgpu_waves_per_eu(2, 2)))
recur_fb(const float* __restrict__ x, const float* __restrict__ W1,
         const float* __restrict__ Wr2T, const float* __restrict__ W2T,
         const float* __restrict__ W4,
         const float* __restrict__ b1, const float* __restrict__ b2,
         const float* __restrict__ br2, const float* __restrict__ b4,
         const float* __restrict__ Vth1, const float* __restrict__ tau1,
         const float* __restrict__ Vth2, const float* __restrict__ tau2,
         const float* __restrict__ tau_out, float* __restrict__ out) {
  const int n = threadIdx.x, b = blockIdx.x;
  const int lane = n & 63, wave = n >> 6;
  const u32 n4 = (u32)(n << 2);
  const u32 nOff = (u32)(n << 11);

  __shared__ float xs[CC];
  __shared__ u64 wordsA[8], wordsB[8];
  __shared__ __align__(16) u32 listA[2][520];
  __shared__ __align__(16) u32 listB[2][520];
  __shared__ int cA[2], cB[2];

  float w1r[CC];  // fits: waves_per_eu(2,2) -> 256-VGPR budget, no spill
  {
    const float4* wp = (const float4*)(W1 + n * CC);
#pragma unroll
    for (int i = 0; i < CC / 4; ++i) {
      float4 q = wp[i];
      w1r[i * 4 + 0] = q.x; w1r[i * 4 + 1] = q.y;
      w1r[i * 4 + 2] = q.z; w1r[i * 4 + 3] = q.w;
    }
  }

  float mem1 = 0.0f, mem2 = 0.0f;
  const float b1v = b1[n], b2v = b2[n], br2v = br2[n];
  const float t1 = tau1[n], t2 = tau2[n];
  const float v1 = Vth1[n], v2 = Vth2[n];
  const float to0 = tau_out[0], to1 = tau_out[1];
  const float b40 = b4[0], b41 = b4[1];
  int sp1 = 0, sp2 = 0, sc1 = 0, sc2 = 0;
  float memo0 = 0.0f, memo1 = 0.0f;

  if (n == 0) { cA[0] = 0; cB[0] = 0; }
  if (n < 8) wordsA[n] = 0ull;
  else if (n < 16) wordsB[n - 8] = 0ull;

  for (int t = 0; t < TT; ++t) {
    const int pp = t & 1, qq = pp ^ 1;
    if (n < CC) xs[n] = x[(b * CC + n) * TT + t];
    __syncthreads();

    float acc = 0.0f;
#pragma unroll
    for (int c = 0; c < CC; ++c) acc = __builtin_fmaf(xs[c], w1r[c], acc);
    float u1 = acc + b1v;
    float r1 = sparse_sum_pre<6>(Wr2T, listA[pp], cA[pp], n4);
    float w1s = r1 + br2v;
    float i1 = u1 + w1s;
    float a1m = t1 * mem1;
    a1m = sp1 ? 0.0f : a1m;
    float m1 = a1m + i1;
    mem1 = m1;
    const int s1 = (m1 - v1) > 0.0f ? 1 : 0;
    u64 ba = __ballot(s1 != 0);
    if (lane == 0) wordsA[wave] = ba;
    __syncthreads();

    build_list(wordsA, s1, wave, nOff, n, listA[qq], &cA[qq]);
    __syncthreads();

    float ff = sparse_sum_pre<6>(W2T, listA[qq], cA[qq], n4);
    float u2 = ff + b2v;
    float r2 = sparse_sum_pre<6>(Wr2T, listB[pp], cB[pp], n4);
    float w2s = r2 + br2v;
    float i2 = u2 + w2s;
    float a2m = t2 * mem2;
    a2m = sp2 ? 0.0f : a2m;
    float m2 = a2m + i2;
    mem2 = m2;
    const int s2 = (m2 - v2) > 0.0f ? 1 : 0;
    u64 bb = __ballot(s2 != 0);
    if (lane == 0) wordsB[wave] = bb;
    sp1 = s1; sp2 = s2; sc1 += s1; sc2 += s2;
    __syncthreads();

    build_list(wordsB, s2, wave, nOff, n, listB[qq], &cB[qq]);

    if (n == 0) {
      float a0 = 0.0f, a1 = 0.0f;
#pragma unroll
      for (int w = 0; w < 8; ++w) {
        u64 m = wordsB[w];
        while (m) {
          int k = (w << 6) + __builtin_ctzll(m);
          m &= m - 1ull;
          a0 += W4[k];
          a1 += W4[NN + k];
        }
      }
      float z0 = to0 * memo0;
      float z1 = to1 * memo1;
      memo0 = z0 + (a0 + b40);
      memo1 = z1 + (a1 + b41);
      out[(b * 2 + 0) * TT + t] = memo0;
      out[(b * 2 + 1) * TT + t] = memo1;
    }
  }

  out[BB * 2 * TT + b * NN + n]           = (float)sc1 / 500.0f;
  out[BB * 2 * TT + BB * NN + b * NN + n] = (float)sc2 / 500.0f;
}

// ---------------- launcher ----------------
extern "C" void kernel_launch(void* const* d_in, const int* in_sizes, int n_in,
                              void* d_out, int out_size, void* d_ws, size_t ws_size,
                              hipStream_t stream) {
  (void)in_sizes; (void)n_in; (void)out_size;
  const float* x    = (const float*)d_in[0];
  const float* W1   = (const float*)d_in[1];
  const float* b1   = (const float*)d_in[2];
  const float* W2   = (const float*)d_in[3];
  const float* b2   = (const float*)d_in[4];
  const float* Wr2  = (const float*)d_in[5];
  const float* br2  = (const float*)d_in[6];
  // d_in[7..10] = W3,b3,Wr3,br3: dead code w.r.t. outputs — skipped
  const float* W4   = (const float*)d_in[11];
  const float* b4   = (const float*)d_in[12];
  const float* Vth1 = (const float*)d_in[13];
  const float* tau1 = (const float*)d_in[14];
  const float* Vth2 = (const float*)d_in[15];
  const float* tau2 = (const float*)d_in[16];
  const float* tau_out = (const float*)d_in[19];

  char* ws = (char*)d_ws;

  // aux: 2 weight tables + 4 state arrays + ballot words + memo
  const size_t aux = 2 * TBL_BYTES + 4 * ST_ARR_BYTES + 512ull * 16 * 8 + 512ull * 2 * 4;

  int chunkT = 0;
  if (ws_size > aux) {
    long long ct = (long long)((ws_size - aux) / CHUNK_ROW_BYTES);
    if (ct > TT) ct = TT;
    ct &= ~1LL;  // even start for every chunk (list parity)
    if (ct >= 16) chunkT = (int)ct;
  }

  if (chunkT >= 16) {
    char* p = ws;
    float* i1ff = (float*)p;  p += (size_t)chunkT * CHUNK_ROW_BYTES;
    float* Wr2T = (float*)p;  p += TBL_BYTES;
    float* W2T  = (float*)p;  p += TBL_BYTES;
    float* stM1 = (float*)p;  p += ST_ARR_BYTES;
    float* stM2 = (float*)p;  p += ST_ARR_BYTES;
    u32* stSC1  = (u32*)p;    p += ST_ARR_BYTES;
    u32* stSC2  = (u32*)p;    p += ST_ARR_BYTES;
    u64* stW    = (u64*)p;    p += 512ull * 16 * 8;
    float* stMemo = (float*)p;

    hipLaunchKernelGGL(prep_weights, dim3((513 * 512 + 255) / 256), dim3(256), 0, stream,
                       W2, Wr2, Wr2T, W2T);
    for (int t0 = 0; t0 < TT; t0 += chunkT) {
      int len = (TT - t0 < chunkT) ? (TT - t0) : chunkT;
      hipLaunchKernelGGL(gemm_i1ff, dim3(BB, (len + T_TILE - 1) / T_TILE), dim3(256), 0,
                         stream, x, W1, i1ff, t0, len);
      hipLaunchKernelGGL(recur2, dim3(BB), dim3(512), 0, stream,
                         i1ff, Wr2T, W2T, W4, b1, b2, br2, b4,
                         Vth1, tau1, Vth2, tau2, tau_out, (float*)d_out,
                         stM1, stM2, stSC1, stSC2, stW, stMemo,
                         t0, len, (t0 == 0) ? 1 : 0, (t0 + len == TT) ? 1 : 0);
    }
  } else {
    float* Wr2T = (float*)ws;
    float* W2T  = (float*)(ws + TBL_BYTES);
    hipLaunchKernelGGL(prep_weights, dim3((513 * 512 + 255) / 256), dim3(256), 0, stream,
                       W2, Wr2, Wr2T, W2T);
    hipLaunchKernelGGL(recur_fb, dim3(BB), dim3(512), 0, stream,
                       x, W1, Wr2T, W2T, W4, b1, b2, br2, b4,
                       Vth1, tau1, Vth2, tau2, tau_out, (float*)d_out);
  }
}

// Round 10
// 2520.118 us; speedup vs baseline: 14.7683x; 1.0762x over previous
//
#include <hip/hip_runtime.h>

// Emulate numpy f32 per-op rounding exactly: no implicit mul+add fusion.
#pragma clang fp contract(off)

typedef unsigned short u16;
typedef unsigned int u32;
typedef unsigned long long u64;

#define BB 512
#define CC 128
#define TT 500
#define NN 512
#define T_TILE 32

#define TBL_BYTES 1050624ull          // 513*512*4
#define W1T_BYTES 262144ull           // 128*512*4
#define CHUNK_ROW_BYTES 1048576ull    // 512*512*4 per timestep
#define ST_ARR_BYTES 1048576ull       // 512*512*4 per state array
#define PAD_OFF (512u << 11)          // byte offset of the all-zero row

// ---------------- prep kernel ----------------
// Transposed weights with a 513th all-zero row used as the padding target so
// sparse loops run in groups of 8 branch-free (adding 0.0f is exact).
// Also transposes W1 -> W1T[c][n] so the gemm's panel staging is a contiguous
// block copy (kills the 4x W1 L2 over-fetch of column-slice staging).
__global__ void prep_weights(const float* __restrict__ W2, const float* __restrict__ Wr2,
                             const float* __restrict__ W1,
                             float* __restrict__ Wr2T, float* __restrict__ W2T,
                             float* __restrict__ W1T) {
  int i = blockIdx.x * blockDim.x + threadIdx.x;
  if (i < 513 * 512) {
    int k = i >> 9, n = i & 511;
    Wr2T[i] = (k < NN) ? Wr2[n * NN + k] : 0.0f;
    W2T[i]  = (k < NN) ? W2[n * NN + k] : 0.0f;
  }
  if (i < CC * NN) {
    // W1T[c*512 + n] = W1[n*128 + c]
    W1T[i] = W1[(i & 511) * CC + (i >> 9)];
  }
}

// ---------------- i1ff GEMM (chunked): i1ff[b][tl][n] = chain_c x[b][c][t]*W1[n][c] ----
// Bit-exact: each output is ONE ascending-c fmaf chain starting at 0.
// r6-proven shape (256 thr, 2 n/thread, 8-c panels) + coalesced staging:
// the panel is now a CONTIGUOUS 16KB copy from W1T (was column-slices of W1
// with ~4x L2 over-read).  LDS 32KB -> up to 5 blocks/CU.
__global__ void __launch_bounds__(256, 4)
gemm_i1ff(const float* __restrict__ x, const float* __restrict__ W1T,
          float* __restrict__ i1ff, int tBeg, int tLen) {
  const int b = blockIdx.x;
  const int tl0 = blockIdx.y * T_TILE;   // chunk-local t of tile start
  const int tid = threadIdx.x;           // 256 threads

  __shared__ __align__(16) float xs[CC * T_TILE];  // [c][j], 16 KB
  __shared__ __align__(16) float W1L[8 * NN];      // [cc][n], 16 KB

  // stage x tile: consecutive threads -> consecutive t (coalesced)
  for (int i = tid; i < CC * T_TILE; i += 256) {
    int c = i >> 5, j = i & 31;
    int tl = tl0 + j;
    xs[c * T_TILE + j] = (tl < tLen) ? x[(b * CC + c) * TT + (tBeg + tl)] : 0.0f;
  }

  float acc[2][T_TILE];
#pragma unroll
  for (int r = 0; r < 2; ++r)
#pragma unroll
    for (int j = 0; j < T_TILE; ++j) acc[r][j] = 0.0f;

  for (int cp = 0; cp < CC / 8; ++cp) {
    __syncthreads();  // guards xs stores (cp==0) and previous-panel reads
    {
      // contiguous panel copy: 4096 floats = 1024 float4 / 256 threads
      const float4* src = (const float4*)(W1T + cp * 8 * NN);
      float4* dst = (float4*)W1L;
#pragma unroll
      for (int k = 0; k < 4; ++k) dst[k * 256 + tid] = src[k * 256 + tid];
    }
    __syncthreads();
#pragma unroll
    for (int cc = 0; cc < 8; ++cc) {
      const int c = cp * 8 + cc;
      float w0 = W1L[cc * NN + tid];         // stride-1 lanes: conflict-free
      float w1 = W1L[cc * NN + tid + 256];
      const float4* xp = (const float4*)(xs + c * T_TILE);
#pragma unroll
      for (int j4 = 0; j4 < T_TILE / 4; ++j4) {
        float4 xq = xp[j4];              // 16B broadcast, conflict-free
        const int j = j4 * 4;
        acc[0][j + 0] = __builtin_fmaf(xq.x, w0, acc[0][j + 0]);
        acc[1][j + 0] = __builtin_fmaf(xq.x, w1, acc[1][j + 0]);
        acc[0][j + 1] = __builtin_fmaf(xq.y, w0, acc[0][j + 1]);
        acc[1][j + 1] = __builtin_fmaf(xq.y, w1, acc[1][j + 1]);
        acc[0][j + 2] = __builtin_fmaf(xq.z, w0, acc[0][j + 2]);
        acc[1][j + 2] = __builtin_fmaf(xq.z, w1, acc[1][j + 2]);
        acc[0][j + 3] = __builtin_fmaf(xq.w, w0, acc[0][j + 3]);
        acc[1][j + 3] = __builtin_fmaf(xq.w, w1, acc[1][j + 3]);
      }
    }
  }

#pragma unroll
  for (int j = 0; j < T_TILE; ++j) {
    int tl = tl0 + j;
    if (tl < tLen) {
      float* o = i1ff + ((size_t)b * tLen + tl) * NN;
      o[tid + 0]   = acc[0][j];
      o[tid + 256] = acc[1][j];
    }
  }
}

// ---------------- sparse row-sum (pre-scaled u32 byte offsets, bit-exact order) ----
// recur2 is AT the aggregate-L2 roofline (r6/r9: 70 GB/dispatch / ~2.03 ms =
// 34.5-34.8 TB/s = the measured ceiling; r3 vs r4: different schedules, same
// time).  Pads hit the L1-resident zero row (~free).  Do not touch.
template <int PRE>
__device__ __forceinline__ float sparse_sum_pre(const float* __restrict__ mat,
                                                const u32* list, int cnt, u32 n4) {
  if (cnt <= 0) return 0.0f;
  const char* base = (const char*)mat;
  const int ng = (cnt + 7) >> 3;
  const int npre = ng < PRE ? ng : PRE;
  float buf[PRE * 8];
#pragma unroll
  for (int g = 0; g < PRE; ++g) {
    if (g < npre) {
      uint4 qa = *(const uint4*)(list + g * 8);
      uint4 qb = *(const uint4*)(list + g * 8 + 4);
      buf[g * 8 + 0] = *(const float*)(base + (qa.x + n4));
      buf[g * 8 + 1] = *(const float*)(base + (qa.y + n4));
      buf[g * 8 + 2] = *(const float*)(base + (qa.z + n4));
      buf[g * 8 + 3] = *(const float*)(base + (qa.w + n4));
      buf[g * 8 + 4] = *(const float*)(base + (qb.x + n4));
      buf[g * 8 + 5] = *(const float*)(base + (qb.y + n4));
      buf[g * 8 + 6] = *(const float*)(base + (qb.z + n4));
      buf[g * 8 + 7] = *(const float*)(base + (qb.w + n4));
    }
  }
  float s = 0.0f;
#pragma unroll
  for (int g = 0; g < PRE; ++g) {
    if (g < npre) {
#pragma unroll
      for (int j = 0; j < 8; ++j) s += buf[g * 8 + j];
    }
  }
  for (int i = PRE * 8; i < cnt; i += 8) {  // rare tail
    uint4 qa = *(const uint4*)(list + i);
    uint4 qb = *(const uint4*)(list + i + 4);
    float f0 = *(const float*)(base + (qa.x + n4));
    float f1 = *(const float*)(base + (qa.y + n4));
    float f2 = *(const float*)(base + (qa.z + n4));
    float f3 = *(const float*)(base + (qa.w + n4));
    float f4 = *(const float*)(base + (qb.x + n4));
    float f5 = *(const float*)(base + (qb.y + n4));
    float f6 = *(const float*)(base + (qb.z + n4));
    float f7 = *(const float*)(base + (qb.w + n4));
    s += f0; s += f1; s += f2; s += f3;
    s += f4; s += f5; s += f6; s += f7;
  }
  return s;
}

// position via v_mbcnt (2 VALU); word totals via readfirstlane -> s_bcnt1 (SALU).
__device__ __forceinline__ void build_list(const u64* words, int mybit, int wave,
                                           u32 nOff, int n, u32* slot, int* cnt) {
  int tot = 0, base = 0;
#pragma unroll
  for (int j = 0; j < 8; ++j) {
    u64 w = words[j];
    u32 lo = __builtin_amdgcn_readfirstlane((u32)w);
    u32 hi = __builtin_amdgcn_readfirstlane((u32)(w >> 32));
    int pj = __popc(lo) + __popc(hi);
    if (j < wave) base += pj;
    tot += pj;
  }
  if (tot) {
    if (mybit) {
      u64 w = words[wave];
      int below = __builtin_amdgcn_mbcnt_hi((u32)(w >> 32),
                    __builtin_amdgcn_mbcnt_lo((u32)w, 0u));
      slot[base + below] = nOff;
    }
    if (n < 8) slot[tot + n] = PAD_OFF;  // pad -> zero row
  }
  if (n == 0) *cnt = tot;
}

// ---------------- chunked recurrent kernel (r6/r9-proven, untouched) ----------------
__global__ void __launch_bounds__(512, 2)
recur2(const float* __restrict__ i1ff, const float* __restrict__ Wr2T,
       const float* __restrict__ W2T, const float* __restrict__ W4,
       const float* __restrict__ b1, const float* __restrict__ b2,
       const float* __restrict__ br2, const float* __restrict__ b4,
       const float* __restrict__ Vth1, const float* __restrict__ tau1,
       const float* __restrict__ Vth2, const float* __restrict__ tau2,
       const float* __restrict__ tau_out, float* __restrict__ out,
       float* __restrict__ stM1, float* __restrict__ stM2,
       u32* __restrict__ stSC1, u32* __restrict__ stSC2,
       u64* __restrict__ stW, float* __restrict__ stMemo,
       int tBeg, int tLen, int isFirst, int isLast) {
  const int n = threadIdx.x, b = blockIdx.x;
  const int lane = n & 63, wave = n >> 6;
  const u32 n4 = (u32)(n << 2);
  const u32 nOff = (u32)(n << 11);

  __shared__ u64 wordsA[8], wordsB[8];
  __shared__ __align__(16) u32 listA[2][520];
  __shared__ __align__(16) u32 listB[2][520];
  __shared__ int cA[2], cB[2];

  float mem1, mem2;
  int sc1, sc2;
  float memo0 = 0.0f, memo1 = 0.0f;
  if (isFirst) {
    mem1 = 0.0f; mem2 = 0.0f; sc1 = 0; sc2 = 0;
    if (n < 8) wordsA[n] = 0ull;
    else if (n < 16) wordsB[n - 8] = 0ull;
  } else {
    mem1 = stM1[b * NN + n]; mem2 = stM2[b * NN + n];
    sc1 = (int)stSC1[b * NN + n]; sc2 = (int)stSC2[b * NN + n];
    if (n < 8) wordsA[n] = stW[b * 16 + n];
    else if (n < 16) wordsB[n - 8] = stW[b * 16 + n];
    if (n == 0) { memo0 = stMemo[b * 2]; memo1 = stMemo[b * 2 + 1]; }
  }
  __syncthreads();
  int sp1 = (int)((wordsA[wave] >> lane) & 1ull);
  int sp2 = (int)((wordsB[wave] >> lane) & 1ull);
  // initial lists into parity slot 0 (tBeg is always even)
  build_list(wordsA, sp1, wave, nOff, n, listA[0], &cA[0]);
  build_list(wordsB, sp2, wave, nOff, n, listB[0], &cB[0]);
  // first in-loop B0 orders these before use

  const float b1v = b1[n], b2v = b2[n], br2v = br2[n];
  const float t1 = tau1[n], t2 = tau2[n];
  const float v1 = Vth1[n], v2 = Vth2[n];
  const float to0 = tau_out[0], to1 = tau_out[1];
  const float b40 = b4[0], b41 = b4[1];

  const float* ffp = i1ff + (size_t)b * tLen * NN + n;
  float ffcur = ffp[0];

  for (int t = tBeg; t < tBeg + tLen; ++t) {
    const int tt = t - tBeg;
    const int pp = t & 1, qq = pp ^ 1;
    const int ttn = (tt + 1 < tLen) ? tt + 1 : tt;
    float ffnext = ffp[(size_t)ttn * NN];   // issued pre-barrier, used next iter
    __syncthreads();  // B0

    // ---- layer 1: i1 = (x@W1^T + b1) + (sp1@Wr2^T + br2) ----
    float r1 = sparse_sum_pre<6>(Wr2T, listA[pp], cA[pp], n4);
    float u1 = ffcur + b1v;
    float w1s = r1 + br2v;
    float i1 = u1 + w1s;
    float a1m = t1 * mem1;
    a1m = sp1 ? 0.0f : a1m;
    float m1 = a1m + i1;
    mem1 = m1;
    const int s1 = (m1 - v1) > 0.0f ? 1 : 0;
    u64 ba = __ballot(s1 != 0);
    if (lane == 0) wordsA[wave] = ba;
    __syncthreads();  // B1

    build_list(wordsA, s1, wave, nOff, n, listA[qq], &cA[qq]);
    __syncthreads();  // B1b

    // ---- layer 2: i2 = (s1@W2^T + b2) + (sp2@Wr2^T + br2) ----
    float ff = sparse_sum_pre<6>(W2T, listA[qq], cA[qq], n4);
    float u2 = ff + b2v;
    float r2 = sparse_sum_pre<6>(Wr2T, listB[pp], cB[pp], n4);
    float w2s = r2 + br2v;
    float i2 = u2 + w2s;
    float a2m = t2 * mem2;
    a2m = sp2 ? 0.0f : a2m;
    float m2 = a2m + i2;
    mem2 = m2;
    const int s2 = (m2 - v2) > 0.0f ? 1 : 0;
    u64 bb = __ballot(s2 != 0);
    if (lane == 0) wordsB[wave] = bb;
    sp1 = s1; sp2 = s2; sc1 += s1; sc2 += s2;
    ffcur = ffnext;
    __syncthreads();  // B2

    build_list(wordsB, s2, wave, nOff, n, listB[qq], &cB[qq]);

    // ---- readout: memo = (tau_out*memo) + ((s2@W4^T) + b4) ----
    if (n == 0) {
      float a0 = 0.0f, a1 = 0.0f;  // ascending-k f32 chains (s2 ~never fires)
#pragma unroll
      for (int w = 0; w < 8; ++w) {
        u64 m = wordsB[w];
        while (m) {
          int k = (w << 6) + __builtin_ctzll(m);
          m &= m - 1ull;
          a0 += W4[k];
          a1 += W4[NN + k];
        }
      }
      float z0 = to0 * memo0;
      float z1 = to1 * memo1;
      memo0 = z0 + (a0 + b40);
      memo1 = z1 + (a1 + b41);
      out[(b * 2 + 0) * TT + t] = memo0;
      out[(b * 2 + 1) * TT + t] = memo1;
    }
  }

  if (isLast) {
    out[BB * 2 * TT + b * NN + n]           = (float)sc1 / 500.0f;
    out[BB * 2 * TT + BB * NN + b * NN + n] = (float)sc2 / 500.0f;
  } else {
    __syncthreads();
    stM1[b * NN + n] = mem1; stM2[b * NN + n] = mem2;
    stSC1[b * NN + n] = (u32)sc1; stSC2[b * NN + n] = (u32)sc2;
    if (n < 8) stW[b * 16 + n] = wordsA[n];
    else if (n < 16) stW[b * 16 + n] = wordsB[n - 8];
    if (n == 0) { stMemo[b * 2] = memo0; stMemo[b * 2 + 1] = memo1; }
  }
}

// ---------------- fallback monolithic kernel (tiny ws): no-spill GEMV ----------------
__global__ void __launch_bounds__(512) __attribute__((amdgpu_waves_per_eu(2, 2)))
recur_fb(const float* __restrict__ x, const float* __restrict__ W1,
         const float* __restrict__ Wr2T, const float* __restrict__ W2T,
         const float* __restrict__ W4,
         const float* __restrict__ b1, const float* __restrict__ b2,
         const float* __restrict__ br2, const float* __restrict__ b4,
         const float* __restrict__ Vth1, const float* __restrict__ tau1,
         const float* __restrict__ Vth2, const float* __restrict__ tau2,
         const float* __restrict__ tau_out, float* __restrict__ out) {
  const int n = threadIdx.x, b = blockIdx.x;
  const int lane = n & 63, wave = n >> 6;
  const u32 n4 = (u32)(n << 2);
  const u32 nOff = (u32)(n << 11);

  __shared__ float xs[CC];
  __shared__ u64 wordsA[8], wordsB[8];
  __shared__ __align__(16) u32 listA[2][520];
  __shared__ __align__(16) u32 listB[2][520];
  __shared__ int cA[2], cB[2];

  float w1r[CC];  // fits: waves_per_eu(2,2) -> 256-VGPR budget, no spill
  {
    const float4* wp = (const float4*)(W1 + n * CC);
#pragma unroll
    for (int i = 0; i < CC / 4; ++i) {
      float4 q = wp[i];
      w1r[i * 4 + 0] = q.x; w1r[i * 4 + 1] = q.y;
      w1r[i * 4 + 2] = q.z; w1r[i * 4 + 3] = q.w;
    }
  }

  float mem1 = 0.0f, mem2 = 0.0f;
  const float b1v = b1[n], b2v = b2[n], br2v = br2[n];
  const float t1 = tau1[n], t2 = tau2[n];
  const float v1 = Vth1[n], v2 = Vth2[n];
  const float to0 = tau_out[0], to1 = tau_out[1];
  const float b40 = b4[0], b41 = b4[1];
  int sp1 = 0, sp2 = 0, sc1 = 0, sc2 = 0;
  float memo0 = 0.0f, memo1 = 0.0f;

  if (n == 0) { cA[0] = 0; cB[0] = 0; }
  if (n < 8) wordsA[n] = 0ull;
  else if (n < 16) wordsB[n - 8] = 0ull;

  for (int t = 0; t < TT; ++t) {
    const int pp = t & 1, qq = pp ^ 1;
    if (n < CC) xs[n] = x[(b * CC + n) * TT + t];
    __syncthreads();

    float acc = 0.0f;
#pragma unroll
    for (int c = 0; c < CC; ++c) acc = __builtin_fmaf(xs[c], w1r[c], acc);
    float u1 = acc + b1v;
    float r1 = sparse_sum_pre<6>(Wr2T, listA[pp], cA[pp], n4);
    float w1s = r1 + br2v;
    float i1 = u1 + w1s;
    float a1m = t1 * mem1;
    a1m = sp1 ? 0.0f : a1m;
    float m1 = a1m + i1;
    mem1 = m1;
    const int s1 = (m1 - v1) > 0.0f ? 1 : 0;
    u64 ba = __ballot(s1 != 0);
    if (lane == 0) wordsA[wave] = ba;
    __syncthreads();

    build_list(wordsA, s1, wave, nOff, n, listA[qq], &cA[qq]);
    __syncthreads();

    float ff = sparse_sum_pre<6>(W2T, listA[qq], cA[qq], n4);
    float u2 = ff + b2v;
    float r2 = sparse_sum_pre<6>(Wr2T, listB[pp], cB[pp], n4);
    float w2s = r2 + br2v;
    float i2 = u2 + w2s;
    float a2m = t2 * mem2;
    a2m = sp2 ? 0.0f : a2m;
    float m2 = a2m + i2;
    mem2 = m2;
    const int s2 = (m2 - v2) > 0.0f ? 1 : 0;
    u64 bb = __ballot(s2 != 0);
    if (lane == 0) wordsB[wave] = bb;
    sp1 = s1; sp2 = s2; sc1 += s1; sc2 += s2;
    __syncthreads();

    build_list(wordsB, s2, wave, nOff, n, listB[qq], &cB[qq]);

    if (n == 0) {
      float a0 = 0.0f, a1 = 0.0f;
#pragma unroll
      for (int w = 0; w < 8; ++w) {
        u64 m = wordsB[w];
        while (m) {
          int k = (w << 6) + __builtin_ctzll(m);
          m &= m - 1ull;
          a0 += W4[k];
          a1 += W4[NN + k];
        }
      }
      float z0 = to0 * memo0;
      float z1 = to1 * memo1;
      memo0 = z0 + (a0 + b40);
      memo1 = z1 + (a1 + b41);
      out[(b * 2 + 0) * TT + t] = memo0;
      out[(b * 2 + 1) * TT + t] = memo1;
    }
  }

  out[BB * 2 * TT + b * NN + n]           = (float)sc1 / 500.0f;
  out[BB * 2 * TT + BB * NN + b * NN + n] = (float)sc2 / 500.0f;
}

// ---------------- launcher ----------------
extern "C" void kernel_launch(void* const* d_in, const int* in_sizes, int n_in,
                              void* d_out, int out_size, void* d_ws, size_t ws_size,
                              hipStream_t stream) {
  (void)in_sizes; (void)n_in; (void)out_size;
  const float* x    = (const float*)d_in[0];
  const float* W1   = (const float*)d_in[1];
  const float* b1   = (const float*)d_in[2];
  const float* W2   = (const float*)d_in[3];
  const float* b2   = (const float*)d_in[4];
  const float* Wr2  = (const float*)d_in[5];
  const float* br2  = (const float*)d_in[6];
  // d_in[7..10] = W3,b3,Wr3,br3: dead code w.r.t. outputs — skipped
  const float* W4   = (const float*)d_in[11];
  const float* b4   = (const float*)d_in[12];
  const float* Vth1 = (const float*)d_in[13];
  const float* tau1 = (const float*)d_in[14];
  const float* Vth2 = (const float*)d_in[15];
  const float* tau2 = (const float*)d_in[16];
  const float* tau_out = (const float*)d_in[19];

  char* ws = (char*)d_ws;

  // aux: 2 weight tables + W1T + 4 state arrays + ballot words + memo
  const size_t aux = 2 * TBL_BYTES + W1T_BYTES + 4 * ST_ARR_BYTES
                   + 512ull * 16 * 8 + 512ull * 2 * 4;

  int chunkT = 0;
  if (ws_size > aux) {
    long long ct = (long long)((ws_size - aux) / CHUNK_ROW_BYTES);
    if (ct > TT) ct = TT;
    ct &= ~1LL;  // even start for every chunk (list parity)
    if (ct >= 16) chunkT = (int)ct;
  }

  if (chunkT >= 16) {
    char* p = ws;
    float* i1ff = (float*)p;  p += (size_t)chunkT * CHUNK_ROW_BYTES;
    float* Wr2T = (float*)p;  p += TBL_BYTES;
    float* W2T  = (float*)p;  p += TBL_BYTES;
    float* W1T  = (float*)p;  p += W1T_BYTES;
    float* stM1 = (float*)p;  p += ST_ARR_BYTES;
    float* stM2 = (float*)p;  p += ST_ARR_BYTES;
    u32* stSC1  = (u32*)p;    p += ST_ARR_BYTES;
    u32* stSC2  = (u32*)p;    p += ST_ARR_BYTES;
    u64* stW    = (u64*)p;    p += 512ull * 16 * 8;
    float* stMemo = (float*)p;

    hipLaunchKernelGGL(prep_weights, dim3((513 * 512 + 255) / 256), dim3(256), 0, stream,
                       W2, Wr2, W1, Wr2T, W2T, W1T);
    for (int t0 = 0; t0 < TT; t0 += chunkT) {
      int len = (TT - t0 < chunkT) ? (TT - t0) : chunkT;
      hipLaunchKernelGGL(gemm_i1ff, dim3(BB, (len + T_TILE - 1) / T_TILE), dim3(256), 0,
                         stream, x, W1T, i1ff, t0, len);
      hipLaunchKernelGGL(recur2, dim3(BB), dim3(512), 0, stream,
                         i1ff, Wr2T, W2T, W4, b1, b2, br2, b4,
                         Vth1, tau1, Vth2, tau2, tau_out, (float*)d_out,
                         stM1, stM2, stSC1, stSC2, stW, stMemo,
                         t0, len, (t0 == 0) ? 1 : 0, (t0 + len == TT) ? 1 : 0);
    }
  } else {
    float* Wr2T = (float*)ws;
    float* W2T  = (float*)(ws + TBL_BYTES);
    float* W1T  = (float*)(ws + 2 * TBL_BYTES);  // unused by fallback; filled anyway
    hipLaunchKernelGGL(prep_weights, dim3((513 * 512 + 255) / 256), dim3(256), 0, stream,
                       W2, Wr2, W1, Wr2T, W2T, W1T);
    hipLaunchKernelGGL(recur_fb, dim3(BB), dim3(512), 0, stream,
                       x, W1, Wr2T, W2T, W4, b1, b2, br2, b4,
                       Vth1, tau1, Vth2, tau2, tau_out, (float*)d_out);
  }
}